// Round 4
// baseline (228.599 us; speedup 1.0000x reference)
//
#include <hip/hip_runtime.h>
#include <math.h>

#define NB 4
#define NS 2048
#define DMODEL 1024
#define DSPACE 64
#define NPOOL 512
#define NHEADS 6
#define NTOK (NB * NS)            // 8192
#define PROJN (NHEADS * DSPACE)   // 384
#define EPSF 1e-8f

// ---------------- K1: normalize neuron_emb rows [0,2048) -> embT[64][2048]
__global__ __launch_bounds__(256) void k_norm_emb(const float* __restrict__ emb,
                                                  float* __restrict__ embT) {
    int row  = blockIdx.x * 4 + (threadIdx.x >> 6);
    int lane = threadIdx.x & 63;
    float v  = emb[row * DSPACE + lane];
    float ss = v * v;
#pragma unroll
    for (int off = 32; off >= 1; off >>= 1) ss += __shfl_xor(ss, off, 64);
    float nrm = sqrtf(ss) + EPSF;
    embT[lane * 2048 + row] = v / nrm;
}

// ---------------- K2: proj = X @ W + b, split-K partials
// BM=256, BN=64, BK=16, 256 threads, 8x8 register tile. grid (32, 6, SK).
__global__ __launch_bounds__(256, 3) void k_proj(const float* __restrict__ X,
                                                 const float* __restrict__ W,
                                                 const float* __restrict__ bias,
                                                 float* __restrict__ P, int KS) {
    __shared__ float Xt[16 * 256];   // [kk][m], 16 KB
    __shared__ float Wt[16 * 64];    // [kk][n], 4 KB
    const int tid = threadIdx.x;
    const int bm  = blockIdx.x * 256;
    const int bn  = blockIdx.y * 64;
    const int z   = blockIdx.z;
    float* Pp = P + (size_t)z * NTOK * PROJN;

    const int r0 = (tid >> 3) << 2;   // 0..124 : rows r0..r0+3 and r0+128..r0+131
    const int c0 = (tid & 7) << 2;    // 0..28  : cols c0..c0+3 and c0+32..c0+35
    const int wr = tid >> 4;          // 0..15
    const int wc = (tid & 15) << 2;   // 0..60

    const float* Xrow = X + (size_t)(bm + tid) * DMODEL;

    float acc[8][8];
#pragma unroll
    for (int i = 0; i < 8; ++i)
#pragma unroll
        for (int j = 0; j < 8; ++j) acc[i][j] = 0.f;

    const int nsteps = KS >> 4;
    int k0 = z * KS;
    float4 xr0 = *(const float4*)&Xrow[k0 + 0];
    float4 xr1 = *(const float4*)&Xrow[k0 + 4];
    float4 xr2 = *(const float4*)&Xrow[k0 + 8];
    float4 xr3 = *(const float4*)&Xrow[k0 + 12];
    float4 wrg = *(const float4*)&W[(size_t)(k0 + wr) * PROJN + bn + wc];

    for (int s = 0; s < nsteps; ++s) {
        __syncthreads();
        Xt[ 0 * 256 + tid] = xr0.x; Xt[ 1 * 256 + tid] = xr0.y;
        Xt[ 2 * 256 + tid] = xr0.z; Xt[ 3 * 256 + tid] = xr0.w;
        Xt[ 4 * 256 + tid] = xr1.x; Xt[ 5 * 256 + tid] = xr1.y;
        Xt[ 6 * 256 + tid] = xr1.z; Xt[ 7 * 256 + tid] = xr1.w;
        Xt[ 8 * 256 + tid] = xr2.x; Xt[ 9 * 256 + tid] = xr2.y;
        Xt[10 * 256 + tid] = xr2.z; Xt[11 * 256 + tid] = xr2.w;
        Xt[12 * 256 + tid] = xr3.x; Xt[13 * 256 + tid] = xr3.y;
        Xt[14 * 256 + tid] = xr3.z; Xt[15 * 256 + tid] = xr3.w;
        *(float4*)&Wt[wr * 64 + wc] = wrg;
        if (s + 1 < nsteps) {
            int k1 = k0 + 16;
            xr0 = *(const float4*)&Xrow[k1 + 0];
            xr1 = *(const float4*)&Xrow[k1 + 4];
            xr2 = *(const float4*)&Xrow[k1 + 8];
            xr3 = *(const float4*)&Xrow[k1 + 12];
            wrg = *(const float4*)&W[(size_t)(k1 + wr) * PROJN + bn + wc];
        }
        __syncthreads();
#pragma unroll
        for (int kk = 0; kk < 16; ++kk) {
            float4 a0 = *(const float4*)&Xt[kk * 256 + r0];
            float4 a1 = *(const float4*)&Xt[kk * 256 + r0 + 128];
            float4 b0 = *(const float4*)&Wt[kk * 64 + c0];
            float4 b1 = *(const float4*)&Wt[kk * 64 + c0 + 32];
            float av[8] = {a0.x, a0.y, a0.z, a0.w, a1.x, a1.y, a1.z, a1.w};
            float bv[8] = {b0.x, b0.y, b0.z, b0.w, b1.x, b1.y, b1.z, b1.w};
#pragma unroll
            for (int i = 0; i < 8; ++i)
#pragma unroll
                for (int j = 0; j < 8; ++j)
                    acc[i][j] = fmaf(av[i], bv[j], acc[i][j]);
        }
        k0 += 16;
    }

    // epilogue: rows {r0+i, r0+128+i}, cols {bn+c0.., bn+c0+32..}; bias on slab 0
#pragma unroll
    for (int i = 0; i < 8; ++i) {
        int row = bm + r0 + ((i < 4) ? i : 124 + i);
        float o0[4], o1[4];
#pragma unroll
        for (int j = 0; j < 4; ++j) { o0[j] = acc[i][j]; o1[j] = acc[i][4 + j]; }
        if (z == 0) {
#pragma unroll
            for (int j = 0; j < 4; ++j) {
                o0[j] += bias[bn + c0 + j];
                o1[j] += bias[bn + c0 + 32 + j];
            }
        }
        *(float4*)&Pp[(size_t)row * PROJN + bn + c0]      = *(float4*)&o0[0];
        *(float4*)&Pp[(size_t)row * PROJN + bn + c0 + 32] = *(float4*)&o1[0];
    }
}

// compare-exchange keeping larger value at index a (descending order)
#define CE(arr, a, b) { float _hi = fmaxf(arr[a], arr[b]); arr[b] = fminf(arr[a], arr[b]); arr[a] = _hi; }

// ---------------- K3: logits + softmax + top8 (merge-butterfly) + dense write
__global__ __launch_bounds__(256, 2) void k_router(const float* __restrict__ P,
                                                   const float* __restrict__ embT,
                                                   float* __restrict__ out, int SK) {
    __shared__ float hsh[32][DSPACE];   // 8 KB
    const int head = blockIdx.y;
    const int t0   = blockIdx.x * 32;
    const int tid  = threadIdx.x;
    const int wid  = tid >> 6;
    const int lane = tid & 63;
    const int so = (head == 2) ? 512 : (head == 3 || head == 4) ? 1024
                 : (head == 5) ? 1536 : 0;

    // stage h tile (sum split-K partials): 32 tokens x 64 dims
    for (int idx = tid; idx < 512; idx += 256) {
        int t  = idx >> 4;
        int d4 = (idx & 15) << 2;
        size_t off = (size_t)(t0 + t) * PROJN + head * DSPACE + d4;
        float4 v = *(const float4*)&P[off];
        for (int ks = 1; ks < SK; ++ks) {
            float4 u = *(const float4*)&P[(size_t)ks * NTOK * PROJN + off];
            v.x += u.x; v.y += u.y; v.z += u.z; v.w += u.w;
        }
        *(float4*)&hsh[t][d4] = v;
    }
    __syncthreads();

    // logits: wave handles 8 tokens; lane owns n = 8*lane + j
    float acc[8][8];
#pragma unroll
    for (int t = 0; t < 8; ++t)
#pragma unroll
        for (int j = 0; j < 8; ++j) acc[t][j] = 0.f;

    for (int d4 = 0; d4 < DSPACE; d4 += 4) {
        float4 hv[8];
#pragma unroll
        for (int t = 0; t < 8; ++t) hv[t] = *(const float4*)&hsh[(wid << 3) + t][d4];
#pragma unroll
        for (int dd = 0; dd < 4; ++dd) {
            const float* er = &embT[(d4 + dd) * 2048 + so + (lane << 3)];
            float e[8];
            *(float4*)&e[0] = *(const float4*)&er[0];
            *(float4*)&e[4] = *(const float4*)&er[4];
#pragma unroll
            for (int t = 0; t < 8; ++t) {
                float hvd = ((const float*)&hv[t])[dd];
#pragma unroll
                for (int j = 0; j < 8; ++j) acc[t][j] = fmaf(hvd, e[j], acc[t][j]);
            }
        }
    }

    const size_t obase = ((size_t)head * NTOK + t0 + (wid << 3)) * NPOOL;

#pragma unroll
    for (int t = 0; t < 8; ++t) {
        float l[8], s[8];
#pragma unroll
        for (int j = 0; j < 8; ++j) { l[j] = acc[t][j]; s[j] = l[j]; }

        // per-lane descending sort of 8 (Batcher odd-even, 19 CE)
        CE(s,0,1) CE(s,2,3) CE(s,4,5) CE(s,6,7)
        CE(s,0,2) CE(s,1,3) CE(s,4,6) CE(s,5,7)
        CE(s,1,2) CE(s,5,6)
        CE(s,0,4) CE(s,1,5) CE(s,2,6) CE(s,3,7)
        CE(s,2,4) CE(s,3,5)
        CE(s,1,2) CE(s,3,4) CE(s,5,6)

        // butterfly merge: after 6 steps every lane holds global top-8 desc
#pragma unroll
        for (int off = 1; off < 64; off <<= 1) {
            float q[8];
#pragma unroll
            for (int i = 0; i < 8; ++i) q[i] = __shfl_xor(s[i], off, 64);
            float c[8];
            c[0] = fmaxf(s[0], q[7]); c[1] = fmaxf(s[1], q[6]);
            c[2] = fmaxf(s[2], q[5]); c[3] = fmaxf(s[3], q[4]);
            c[4] = fmaxf(s[4], q[3]); c[5] = fmaxf(s[5], q[2]);
            c[6] = fmaxf(s[6], q[1]); c[7] = fmaxf(s[7], q[0]);
            CE(c,0,4) CE(c,1,5) CE(c,2,6) CE(c,3,7)
            CE(c,0,2) CE(c,1,3) CE(c,4,6) CE(c,5,7)
            CE(c,0,1) CE(c,2,3) CE(c,4,5) CE(c,6,7)
#pragma unroll
            for (int i = 0; i < 8; ++i) s[i] = c[i];
        }

        const float T = s[7];    // 8th largest
        const float m = s[0];    // row max

        float e[8]; float zl = 0.f;
#pragma unroll
        for (int j = 0; j < 8; ++j) { e[j] = __expf(l[j] - m); zl += e[j]; }
        // NOTE: EPS*Z term uses lane-local zl (rel. error <= ~5e-6, deterministic)

        unsigned gtm = 0, eqm = 0; int cgt = 0, ceq = 0;
#pragma unroll
        for (int j = 0; j < 8; ++j) {
            if (l[j] > T)       { gtm |= 1u << j; ++cgt; }
            else if (l[j] == T) { eqm |= 1u << j; ++ceq; }
        }
        int own = (ceq << 8) | cgt;
        int inc = own;
#pragma unroll
        for (int off = 1; off < 64; off <<= 1) {
            int v = __shfl_up(inc, off, 64);
            if (lane >= off) inc += v;
        }
        int tot  = __shfl(inc, 63, 64);
        int need = 8 - (tot & 0xff);
        int eqpre = (inc - own) >> 8;
        unsigned sel = gtm;
#pragma unroll
        for (int j = 0; j < 8; ++j) {
            if ((eqm >> j) & 1u) { if (eqpre < need) sel |= 1u << j; ++eqpre; }
        }

        float s8 = 0.f;
#pragma unroll
        for (int i = 0; i < 8; ++i) s8 += __expf(s[i] - m);
        float invd = 1.0f / (s8 + EPSF * zl);

        float o[8];
#pragma unroll
        for (int j = 0; j < 8; ++j)
            o[j] = ((sel >> j) & 1u) ? e[j] * invd : 0.0f;
        float4* dst = (float4*)&out[obase + (size_t)t * NPOOL + (lane << 3)];
        dst[0] = *(float4*)&o[0];
        dst[1] = *(float4*)&o[4];
    }
}

extern "C" void kernel_launch(void* const* d_in, const int* in_sizes, int n_in,
                              void* d_out, int out_size, void* d_ws, size_t ws_size,
                              hipStream_t stream) {
    const float* x   = (const float*)d_in[0];
    const float* W   = (const float*)d_in[1];
    const float* b   = (const float*)d_in[2];
    const float* emb = (const float*)d_in[3];
    float* out  = (float*)d_out;
    float* embT = (float*)d_ws;                       // 64*2048 f32 = 512 KB
    float* proj = embT + 64 * 2048;                   // SK slabs of 8192*384 f32

    size_t base = (size_t)64 * 2048 * 4;
    size_t slab = (size_t)NTOK * PROJN * 4;           // 12.58 MB
    int SK = (ws_size >= base + 4 * slab) ? 4
           : (ws_size >= base + 2 * slab) ? 2 : 1;
    int KS = DMODEL / SK;

    k_norm_emb<<<dim3(512), dim3(256), 0, stream>>>(emb, embT);
    dim3 g2(NTOK / 256, PROJN / 64, SK);
    k_proj<<<g2, dim3(256), 0, stream>>>(x, W, b, proj, KS);
    dim3 g3(NTOK / 32, NHEADS);
    k_router<<<g3, dim3(256), 0, stream>>>(proj, embT, out, SK);
}

// Round 5
// 179.013 us; speedup vs baseline: 1.2770x; 1.2770x over previous
//
#include <hip/hip_runtime.h>
#include <math.h>

#define NB 4
#define NS 2048
#define DMODEL 1024
#define DSPACE 64
#define NPOOL 512
#define NHEADS 6
#define NTOK (NB * NS)            // 8192
#define PROJN (NHEADS * DSPACE)   // 384
#define EPSF 1e-8f

// ---------------- K1: normalize neuron_emb rows [0,2048) -> embT[64][2048]
__global__ __launch_bounds__(256) void k_norm_emb(const float* __restrict__ emb,
                                                  float* __restrict__ embT) {
    int row  = blockIdx.x * 4 + (threadIdx.x >> 6);
    int lane = threadIdx.x & 63;
    float v  = emb[row * DSPACE + lane];
    float ss = v * v;
#pragma unroll
    for (int off = 32; off >= 1; off >>= 1) ss += __shfl_xor(ss, off, 64);
    float nrm = sqrtf(ss) + EPSF;
    embT[lane * 2048 + row] = v / nrm;
}

// ---------------- K2: proj = X @ W + b, split-K partials
// BM=256, BN=64, BK=16, 256 threads, 8x8 register tile. grid (32, 6, SK).
// launch_bounds (256,2): 128-VGPR budget -- acc[8][8] (64) + prefetch (17)
// + operands/addressing fits ~110 with NO spill. (256,3) spilled acc -> 160us.
__global__ __launch_bounds__(256, 2) void k_proj(const float* __restrict__ X,
                                                 const float* __restrict__ W,
                                                 const float* __restrict__ bias,
                                                 float* __restrict__ P, int KS) {
    __shared__ float Xt[16 * 256];   // [kk][m], 16 KB
    __shared__ float Wt[16 * 64];    // [kk][n], 4 KB
    const int tid = threadIdx.x;
    const int bm  = blockIdx.x * 256;
    const int bn  = blockIdx.y * 64;
    const int z   = blockIdx.z;
    float* Pp = P + (size_t)z * NTOK * PROJN;

    const int r0 = (tid >> 3) << 2;   // 0..124 : rows r0..r0+3 and r0+128..r0+131
    const int c0 = (tid & 7) << 2;    // 0..28  : cols c0..c0+3 and c0+32..c0+35
    const int wr = tid >> 4;          // 0..15
    const int wc = (tid & 15) << 2;   // 0..60

    const float* Xrow = X + (size_t)(bm + tid) * DMODEL;

    float acc[8][8];
#pragma unroll
    for (int i = 0; i < 8; ++i)
#pragma unroll
        for (int j = 0; j < 8; ++j) acc[i][j] = 0.f;

    const int nsteps = KS >> 4;
    int k0 = z * KS;
    float4 xr0 = *(const float4*)&Xrow[k0 + 0];
    float4 xr1 = *(const float4*)&Xrow[k0 + 4];
    float4 xr2 = *(const float4*)&Xrow[k0 + 8];
    float4 xr3 = *(const float4*)&Xrow[k0 + 12];
    float4 wrg = *(const float4*)&W[(size_t)(k0 + wr) * PROJN + bn + wc];

    for (int s = 0; s < nsteps; ++s) {
        __syncthreads();
        Xt[ 0 * 256 + tid] = xr0.x; Xt[ 1 * 256 + tid] = xr0.y;
        Xt[ 2 * 256 + tid] = xr0.z; Xt[ 3 * 256 + tid] = xr0.w;
        Xt[ 4 * 256 + tid] = xr1.x; Xt[ 5 * 256 + tid] = xr1.y;
        Xt[ 6 * 256 + tid] = xr1.z; Xt[ 7 * 256 + tid] = xr1.w;
        Xt[ 8 * 256 + tid] = xr2.x; Xt[ 9 * 256 + tid] = xr2.y;
        Xt[10 * 256 + tid] = xr2.z; Xt[11 * 256 + tid] = xr2.w;
        Xt[12 * 256 + tid] = xr3.x; Xt[13 * 256 + tid] = xr3.y;
        Xt[14 * 256 + tid] = xr3.z; Xt[15 * 256 + tid] = xr3.w;
        *(float4*)&Wt[wr * 64 + wc] = wrg;
        if (s + 1 < nsteps) {
            int k1 = k0 + 16;
            xr0 = *(const float4*)&Xrow[k1 + 0];
            xr1 = *(const float4*)&Xrow[k1 + 4];
            xr2 = *(const float4*)&Xrow[k1 + 8];
            xr3 = *(const float4*)&Xrow[k1 + 12];
            wrg = *(const float4*)&W[(size_t)(k1 + wr) * PROJN + bn + wc];
        }
        __syncthreads();
#pragma unroll
        for (int kk = 0; kk < 16; ++kk) {
            float4 a0 = *(const float4*)&Xt[kk * 256 + r0];
            float4 a1 = *(const float4*)&Xt[kk * 256 + r0 + 128];
            float4 b0 = *(const float4*)&Wt[kk * 64 + c0];
            float4 b1 = *(const float4*)&Wt[kk * 64 + c0 + 32];
            float av[8] = {a0.x, a0.y, a0.z, a0.w, a1.x, a1.y, a1.z, a1.w};
            float bv[8] = {b0.x, b0.y, b0.z, b0.w, b1.x, b1.y, b1.z, b1.w};
#pragma unroll
            for (int i = 0; i < 8; ++i)
#pragma unroll
                for (int j = 0; j < 8; ++j)
                    acc[i][j] = fmaf(av[i], bv[j], acc[i][j]);
        }
        k0 += 16;
    }

    // epilogue: rows {r0+i, r0+128+i}, cols {bn+c0.., bn+c0+32..}; bias on slab 0
#pragma unroll
    for (int i = 0; i < 8; ++i) {
        int row = bm + r0 + ((i < 4) ? i : 124 + i);
        float o0[4], o1[4];
#pragma unroll
        for (int j = 0; j < 4; ++j) { o0[j] = acc[i][j]; o1[j] = acc[i][4 + j]; }
        if (z == 0) {
#pragma unroll
            for (int j = 0; j < 4; ++j) {
                o0[j] += bias[bn + c0 + j];
                o1[j] += bias[bn + c0 + 32 + j];
            }
        }
        *(float4*)&Pp[(size_t)row * PROJN + bn + c0]      = *(float4*)&o0[0];
        *(float4*)&Pp[(size_t)row * PROJN + bn + c0 + 32] = *(float4*)&o1[0];
    }
}

// compare-exchange keeping larger value at index a (descending order)
#define CE(arr, a, b) { float _hi = fmaxf(arr[a], arr[b]); arr[b] = fminf(arr[a], arr[b]); arr[a] = _hi; }

// ---------------- K3: logits + softmax + top8 (merge-butterfly) + dense write
__global__ __launch_bounds__(256, 2) void k_router(const float* __restrict__ P,
                                                   const float* __restrict__ embT,
                                                   float* __restrict__ out, int SK) {
    __shared__ float hsh[32][DSPACE];   // 8 KB
    const int head = blockIdx.y;
    const int t0   = blockIdx.x * 32;
    const int tid  = threadIdx.x;
    const int wid  = tid >> 6;
    const int lane = tid & 63;
    const int so = (head == 2) ? 512 : (head == 3 || head == 4) ? 1024
                 : (head == 5) ? 1536 : 0;

    // stage h tile (sum split-K partials): 32 tokens x 64 dims
    for (int idx = tid; idx < 512; idx += 256) {
        int t  = idx >> 4;
        int d4 = (idx & 15) << 2;
        size_t off = (size_t)(t0 + t) * PROJN + head * DSPACE + d4;
        float4 v = *(const float4*)&P[off];
        for (int ks = 1; ks < SK; ++ks) {
            float4 u = *(const float4*)&P[(size_t)ks * NTOK * PROJN + off];
            v.x += u.x; v.y += u.y; v.z += u.z; v.w += u.w;
        }
        *(float4*)&hsh[t][d4] = v;
    }
    __syncthreads();

    // logits: wave handles 8 tokens; lane owns n = 8*lane + j
    float acc[8][8];
#pragma unroll
    for (int t = 0; t < 8; ++t)
#pragma unroll
        for (int j = 0; j < 8; ++j) acc[t][j] = 0.f;

    for (int d4 = 0; d4 < DSPACE; d4 += 4) {
        float4 hv[8];
#pragma unroll
        for (int t = 0; t < 8; ++t) hv[t] = *(const float4*)&hsh[(wid << 3) + t][d4];
#pragma unroll
        for (int dd = 0; dd < 4; ++dd) {
            const float* er = &embT[(d4 + dd) * 2048 + so + (lane << 3)];
            float e[8];
            *(float4*)&e[0] = *(const float4*)&er[0];
            *(float4*)&e[4] = *(const float4*)&er[4];
#pragma unroll
            for (int t = 0; t < 8; ++t) {
                float hvd = ((const float*)&hv[t])[dd];
#pragma unroll
                for (int j = 0; j < 8; ++j) acc[t][j] = fmaf(hvd, e[j], acc[t][j]);
            }
        }
    }

    const size_t obase = ((size_t)head * NTOK + t0 + (wid << 3)) * NPOOL;

#pragma unroll
    for (int t = 0; t < 8; ++t) {
        float l[8], s[8];
#pragma unroll
        for (int j = 0; j < 8; ++j) { l[j] = acc[t][j]; s[j] = l[j]; }

        // per-lane descending sort of 8 (Batcher odd-even, 19 CE)
        CE(s,0,1) CE(s,2,3) CE(s,4,5) CE(s,6,7)
        CE(s,0,2) CE(s,1,3) CE(s,4,6) CE(s,5,7)
        CE(s,1,2) CE(s,5,6)
        CE(s,0,4) CE(s,1,5) CE(s,2,6) CE(s,3,7)
        CE(s,2,4) CE(s,3,5)
        CE(s,1,2) CE(s,3,4) CE(s,5,6)

        // butterfly merge: after 6 steps every lane holds global top-8 desc
#pragma unroll
        for (int off = 1; off < 64; off <<= 1) {
            float q[8];
#pragma unroll
            for (int i = 0; i < 8; ++i) q[i] = __shfl_xor(s[i], off, 64);
            float c[8];
            c[0] = fmaxf(s[0], q[7]); c[1] = fmaxf(s[1], q[6]);
            c[2] = fmaxf(s[2], q[5]); c[3] = fmaxf(s[3], q[4]);
            c[4] = fmaxf(s[4], q[3]); c[5] = fmaxf(s[5], q[2]);
            c[6] = fmaxf(s[6], q[1]); c[7] = fmaxf(s[7], q[0]);
            CE(c,0,4) CE(c,1,5) CE(c,2,6) CE(c,3,7)
            CE(c,0,2) CE(c,1,3) CE(c,4,6) CE(c,5,7)
            CE(c,0,1) CE(c,2,3) CE(c,4,5) CE(c,6,7)
#pragma unroll
            for (int i = 0; i < 8; ++i) s[i] = c[i];
        }

        const float T = s[7];    // 8th largest
        const float m = s[0];    // row max

        float e[8]; float zl = 0.f;
#pragma unroll
        for (int j = 0; j < 8; ++j) { e[j] = __expf(l[j] - m); zl += e[j]; }
        // EPS*Z term uses lane-local zl (rel. error <= ~5e-6, deterministic)

        unsigned gtm = 0, eqm = 0; int cgt = 0, ceq = 0;
#pragma unroll
        for (int j = 0; j < 8; ++j) {
            if (l[j] > T)       { gtm |= 1u << j; ++cgt; }
            else if (l[j] == T) { eqm |= 1u << j; ++ceq; }
        }
        int own = (ceq << 8) | cgt;
        int inc = own;
#pragma unroll
        for (int off = 1; off < 64; off <<= 1) {
            int v = __shfl_up(inc, off, 64);
            if (lane >= off) inc += v;
        }
        int tot  = __shfl(inc, 63, 64);
        int need = 8 - (tot & 0xff);
        int eqpre = (inc - own) >> 8;
        unsigned sel = gtm;
#pragma unroll
        for (int j = 0; j < 8; ++j) {
            if ((eqm >> j) & 1u) { if (eqpre < need) sel |= 1u << j; ++eqpre; }
        }

        float s8 = 0.f;
#pragma unroll
        for (int i = 0; i < 8; ++i) s8 += __expf(s[i] - m);
        float invd = 1.0f / (s8 + EPSF * zl);

        float o[8];
#pragma unroll
        for (int j = 0; j < 8; ++j)
            o[j] = ((sel >> j) & 1u) ? e[j] * invd : 0.0f;
        float4* dst = (float4*)&out[obase + (size_t)t * NPOOL + (lane << 3)];
        dst[0] = *(float4*)&o[0];
        dst[1] = *(float4*)&o[4];
    }
}

extern "C" void kernel_launch(void* const* d_in, const int* in_sizes, int n_in,
                              void* d_out, int out_size, void* d_ws, size_t ws_size,
                              hipStream_t stream) {
    const float* x   = (const float*)d_in[0];
    const float* W   = (const float*)d_in[1];
    const float* b   = (const float*)d_in[2];
    const float* emb = (const float*)d_in[3];
    float* out  = (float*)d_out;
    float* embT = (float*)d_ws;                       // 64*2048 f32 = 512 KB
    float* proj = embT + 64 * 2048;                   // SK slabs of 8192*384 f32

    size_t base = (size_t)64 * 2048 * 4;
    size_t slab = (size_t)NTOK * PROJN * 4;           // 12.58 MB
    int SK = (ws_size >= base + 4 * slab) ? 4
           : (ws_size >= base + 2 * slab) ? 2 : 1;
    int KS = DMODEL / SK;

    k_norm_emb<<<dim3(512), dim3(256), 0, stream>>>(emb, embT);
    dim3 g2(NTOK / 256, PROJN / 64, SK);
    k_proj<<<g2, dim3(256), 0, stream>>>(x, W, b, proj, KS);
    dim3 g3(NTOK / 32, NHEADS);
    k_router<<<g3, dim3(256), 0, stream>>>(proj, embT, out, SK);
}

// Round 6
// 177.804 us; speedup vs baseline: 1.2857x; 1.0068x over previous
//
#include <hip/hip_runtime.h>
#include <math.h>

#define NB 4
#define NS 2048
#define DMODEL 1024
#define DSPACE 64
#define NPOOL 512
#define NHEADS 6
#define NTOK (NB * NS)            // 8192
#define PROJN (NHEADS * DSPACE)   // 384
#define EPSF 1e-8f

typedef float f32x2 __attribute__((ext_vector_type(2)));

// packed f32 FMA: both halves multiply by S1.lo / S1.hi (broadcast via op_sel)
#define PK_LO(ACC, A2, B2) \
    asm("v_pk_fma_f32 %0, %1, %2, %0 op_sel:[0,0,0] op_sel_hi:[1,0,1]" \
        : "+v"(ACC) : "v"(A2), "v"(B2))
#define PK_HI(ACC, A2, B2) \
    asm("v_pk_fma_f32 %0, %1, %2, %0 op_sel:[0,1,0] op_sel_hi:[1,1,1]" \
        : "+v"(ACC) : "v"(A2), "v"(B2))

// ---------------- K1: normalize neuron_emb rows [0,2048) -> embT[64][2048]
__global__ __launch_bounds__(256) void k_norm_emb(const float* __restrict__ emb,
                                                  float* __restrict__ embT) {
    int row  = blockIdx.x * 4 + (threadIdx.x >> 6);
    int lane = threadIdx.x & 63;
    float v  = emb[row * DSPACE + lane];
    float ss = v * v;
#pragma unroll
    for (int off = 32; off >= 1; off >>= 1) ss += __shfl_xor(ss, off, 64);
    float nrm = sqrtf(ss) + EPSF;
    embT[lane * 2048 + row] = v / nrm;
}

// ---------------- K2: proj = X @ W + b, split-K partials, packed-f32 FMA
// BM=256, BN=64, BK=16, 256 threads, 8x8 per-thread tile, dbuf LDS.
__global__ __launch_bounds__(256, 2) void k_proj(const float* __restrict__ X,
                                                 const float* __restrict__ W,
                                                 const float* __restrict__ bias,
                                                 float* __restrict__ P, int KS) {
    __shared__ float Xt[2][16 * 256];   // 32 KB
    __shared__ float Wt[2][16 * 64];    // 8 KB
    const int tid = threadIdx.x;
    const int bm  = blockIdx.x * 256;
    const int bn  = blockIdx.y * 64;
    const int z   = blockIdx.z;
    float* Pp = P + (size_t)z * NTOK * PROJN;

    const int r0  = (tid >> 3) << 2;   // 0..124
    const int c0  = (tid & 7) << 2;    // 0..28
    const int lwr = tid >> 4;          // 0..15
    const int lwc = (tid & 15) << 2;   // 0..60

    const float* Xrow = X + (size_t)(bm + tid) * DMODEL;

    f32x2 acc2[4][8];                  // [row-pair][col]
#pragma unroll
    for (int p = 0; p < 4; ++p)
#pragma unroll
        for (int j = 0; j < 8; ++j) acc2[p][j] = (f32x2){0.f, 0.f};

    const int nsteps = KS >> 4;
    int k0 = z * KS;
    float4 xr0 = *(const float4*)&Xrow[k0 + 0];
    float4 xr1 = *(const float4*)&Xrow[k0 + 4];
    float4 xr2 = *(const float4*)&Xrow[k0 + 8];
    float4 xr3 = *(const float4*)&Xrow[k0 + 12];
    float4 wrg = *(const float4*)&W[(size_t)(k0 + lwr) * PROJN + bn + lwc];

    {   // prologue: stage tile 0 into buffer 0
        float* xb = Xt[0]; float* wb = Wt[0];
        xb[ 0*256+tid]=xr0.x; xb[ 1*256+tid]=xr0.y; xb[ 2*256+tid]=xr0.z; xb[ 3*256+tid]=xr0.w;
        xb[ 4*256+tid]=xr1.x; xb[ 5*256+tid]=xr1.y; xb[ 6*256+tid]=xr1.z; xb[ 7*256+tid]=xr1.w;
        xb[ 8*256+tid]=xr2.x; xb[ 9*256+tid]=xr2.y; xb[10*256+tid]=xr2.z; xb[11*256+tid]=xr2.w;
        xb[12*256+tid]=xr3.x; xb[13*256+tid]=xr3.y; xb[14*256+tid]=xr3.z; xb[15*256+tid]=xr3.w;
        *(float4*)&wb[lwr * 64 + lwc] = wrg;
    }

    for (int s = 0; s < nsteps; ++s) {
        if (s + 1 < nsteps) {          // issue next-tile global loads early
            int k1 = k0 + 16;
            xr0 = *(const float4*)&Xrow[k1 + 0];
            xr1 = *(const float4*)&Xrow[k1 + 4];
            xr2 = *(const float4*)&Xrow[k1 + 8];
            xr3 = *(const float4*)&Xrow[k1 + 12];
            wrg = *(const float4*)&W[(size_t)(k1 + lwr) * PROJN + bn + lwc];
        }
        __syncthreads();               // buf[s&1] ready for all waves
        if (s + 1 < nsteps) {          // stage next tile into other buffer
            float* xb = Xt[(s + 1) & 1]; float* wb = Wt[(s + 1) & 1];
            xb[ 0*256+tid]=xr0.x; xb[ 1*256+tid]=xr0.y; xb[ 2*256+tid]=xr0.z; xb[ 3*256+tid]=xr0.w;
            xb[ 4*256+tid]=xr1.x; xb[ 5*256+tid]=xr1.y; xb[ 6*256+tid]=xr1.z; xb[ 7*256+tid]=xr1.w;
            xb[ 8*256+tid]=xr2.x; xb[ 9*256+tid]=xr2.y; xb[10*256+tid]=xr2.z; xb[11*256+tid]=xr2.w;
            xb[12*256+tid]=xr3.x; xb[13*256+tid]=xr3.y; xb[14*256+tid]=xr3.z; xb[15*256+tid]=xr3.w;
            *(float4*)&wb[lwr * 64 + lwc] = wrg;
        }
        const float* xc = Xt[s & 1];
        const float* wc = Wt[s & 1];
#pragma unroll
        for (int kk = 0; kk < 16; ++kk) {
            const float* xr = &xc[kk * 256];
            const float* wr = &wc[kk * 64];
            f32x2 ap0 = *(const f32x2*)&xr[r0];
            f32x2 ap1 = *(const f32x2*)&xr[r0 + 2];
            f32x2 ap2 = *(const f32x2*)&xr[r0 + 128];
            f32x2 ap3 = *(const f32x2*)&xr[r0 + 130];
            f32x2 bq0 = *(const f32x2*)&wr[c0];
            f32x2 bq1 = *(const f32x2*)&wr[c0 + 2];
            f32x2 bq2 = *(const f32x2*)&wr[c0 + 32];
            f32x2 bq3 = *(const f32x2*)&wr[c0 + 34];
#pragma unroll
            for (int p = 0; p < 4; ++p) {
                f32x2 ap = (p == 0) ? ap0 : (p == 1) ? ap1 : (p == 2) ? ap2 : ap3;
                PK_LO(acc2[p][0], ap, bq0); PK_HI(acc2[p][1], ap, bq0);
                PK_LO(acc2[p][2], ap, bq1); PK_HI(acc2[p][3], ap, bq1);
                PK_LO(acc2[p][4], ap, bq2); PK_HI(acc2[p][5], ap, bq2);
                PK_LO(acc2[p][6], ap, bq3); PK_HI(acc2[p][7], ap, bq3);
            }
        }
        k0 += 16;
    }

    // epilogue: rows {r0..r0+3, r0+128..r0+131}; bias on slab 0
#pragma unroll
    for (int i = 0; i < 8; ++i) {
        int row = bm + r0 + ((i < 4) ? i : 124 + i);
        float o0[4], o1[4];
#pragma unroll
        for (int j = 0; j < 4; ++j) {
            f32x2 v0 = acc2[i >> 1][j];
            f32x2 v1 = acc2[i >> 1][j + 4];
            o0[j] = (i & 1) ? v0.y : v0.x;
            o1[j] = (i & 1) ? v1.y : v1.x;
        }
        if (z == 0) {
#pragma unroll
            for (int j = 0; j < 4; ++j) {
                o0[j] += bias[bn + c0 + j];
                o1[j] += bias[bn + c0 + 32 + j];
            }
        }
        *(float4*)&Pp[(size_t)row * PROJN + bn + c0]      = *(float4*)&o0[0];
        *(float4*)&Pp[(size_t)row * PROJN + bn + c0 + 32] = *(float4*)&o1[0];
    }
}

// compare-exchange keeping larger value at index a (descending order)
#define CE(arr, a, b) { float _hi = fmaxf(arr[a], arr[b]); arr[b] = fminf(arr[a], arr[b]); arr[a] = _hi; }

// ---------------- K3: logits (packed f32) + softmax + top8 + dense write
__global__ __launch_bounds__(256, 2) void k_router(const float* __restrict__ P,
                                                   const float* __restrict__ embT,
                                                   float* __restrict__ out, int SK) {
    __shared__ float hsh[32][DSPACE];   // 8 KB
    const int head = blockIdx.y;
    const int t0   = blockIdx.x * 32;
    const int tid  = threadIdx.x;
    const int wid  = tid >> 6;
    const int lane = tid & 63;
    const int so = (head == 2) ? 512 : (head == 3 || head == 4) ? 1024
                 : (head == 5) ? 1536 : 0;

    // stage h tile (sum split-K partials): 32 tokens x 64 dims
    for (int idx = tid; idx < 512; idx += 256) {
        int t  = idx >> 4;
        int d4 = (idx & 15) << 2;
        size_t off = (size_t)(t0 + t) * PROJN + head * DSPACE + d4;
        float4 v = *(const float4*)&P[off];
        for (int ks = 1; ks < SK; ++ks) {
            float4 u = *(const float4*)&P[(size_t)ks * NTOK * PROJN + off];
            v.x += u.x; v.y += u.y; v.z += u.z; v.w += u.w;
        }
        *(float4*)&hsh[t][d4] = v;
    }
    __syncthreads();

    // logits: wave handles 8 tokens; lane owns n = 8*lane + j (4 f32x2 pairs)
    f32x2 acc2[8][4];
#pragma unroll
    for (int t = 0; t < 8; ++t)
#pragma unroll
        for (int p = 0; p < 4; ++p) acc2[t][p] = (f32x2){0.f, 0.f};

    const float* ebase = &embT[so + (lane << 3)];
    for (int d4 = 0; d4 < DSPACE; d4 += 4) {
        f32x2 hp[8][2];
#pragma unroll
        for (int t = 0; t < 8; ++t) {
            hp[t][0] = *(const f32x2*)&hsh[(wid << 3) + t][d4];
            hp[t][1] = *(const f32x2*)&hsh[(wid << 3) + t][d4 + 2];
        }
#pragma unroll
        for (int dp = 0; dp < 2; ++dp) {
            const float* er0 = ebase + (size_t)(d4 + 2 * dp) * 2048;
            const float* er1 = er0 + 2048;
            f32x2 ea[4], eb[4];
#pragma unroll
            for (int p = 0; p < 4; ++p) {
                ea[p] = *(const f32x2*)&er0[2 * p];
                eb[p] = *(const f32x2*)&er1[2 * p];
            }
#pragma unroll
            for (int t = 0; t < 8; ++t) {
#pragma unroll
                for (int p = 0; p < 4; ++p) {
                    PK_LO(acc2[t][p], ea[p], hp[t][dp]);   // d even: hv .lo
                    PK_HI(acc2[t][p], eb[p], hp[t][dp]);   // d odd : hv .hi
                }
            }
        }
    }

    const size_t obase = ((size_t)head * NTOK + t0 + (wid << 3)) * NPOOL;

#pragma unroll
    for (int t = 0; t < 8; ++t) {
        float l[8], s[8];
#pragma unroll
        for (int j = 0; j < 8; ++j) {
            f32x2 v = acc2[t][j >> 1];
            l[j] = (j & 1) ? v.y : v.x;
            s[j] = l[j];
        }

        // per-lane descending sort of 8 (Batcher odd-even, 19 CE)
        CE(s,0,1) CE(s,2,3) CE(s,4,5) CE(s,6,7)
        CE(s,0,2) CE(s,1,3) CE(s,4,6) CE(s,5,7)
        CE(s,1,2) CE(s,5,6)
        CE(s,0,4) CE(s,1,5) CE(s,2,6) CE(s,3,7)
        CE(s,2,4) CE(s,3,5)
        CE(s,1,2) CE(s,3,4) CE(s,5,6)

        // butterfly merge: after 6 steps every lane holds global top-8 desc
#pragma unroll
        for (int off = 1; off < 64; off <<= 1) {
            float q[8];
#pragma unroll
            for (int i = 0; i < 8; ++i) q[i] = __shfl_xor(s[i], off, 64);
            float c[8];
            c[0] = fmaxf(s[0], q[7]); c[1] = fmaxf(s[1], q[6]);
            c[2] = fmaxf(s[2], q[5]); c[3] = fmaxf(s[3], q[4]);
            c[4] = fmaxf(s[4], q[3]); c[5] = fmaxf(s[5], q[2]);
            c[6] = fmaxf(s[6], q[1]); c[7] = fmaxf(s[7], q[0]);
            CE(c,0,4) CE(c,1,5) CE(c,2,6) CE(c,3,7)
            CE(c,0,2) CE(c,1,3) CE(c,4,6) CE(c,5,7)
            CE(c,0,1) CE(c,2,3) CE(c,4,5) CE(c,6,7)
#pragma unroll
            for (int i = 0; i < 8; ++i) s[i] = c[i];
        }

        const float T = s[7];    // 8th largest
        const float m = s[0];    // row max

        float e[8]; float zl = 0.f;
#pragma unroll
        for (int j = 0; j < 8; ++j) { e[j] = __expf(l[j] - m); zl += e[j]; }
        // EPS*Z term uses lane-local zl (rel. error <= ~5e-6, deterministic)

        unsigned gtm = 0, eqm = 0; int cgt = 0, ceq = 0;
#pragma unroll
        for (int j = 0; j < 8; ++j) {
            if (l[j] > T)       { gtm |= 1u << j; ++cgt; }
            else if (l[j] == T) { eqm |= 1u << j; ++ceq; }
        }
        int own = (ceq << 8) | cgt;
        int inc = own;
#pragma unroll
        for (int off = 1; off < 64; off <<= 1) {
            int v = __shfl_up(inc, off, 64);
            if (lane >= off) inc += v;
        }
        int tot  = __shfl(inc, 63, 64);
        int need = 8 - (tot & 0xff);
        int eqpre = (inc - own) >> 8;
        unsigned sel = gtm;
#pragma unroll
        for (int j = 0; j < 8; ++j) {
            if ((eqm >> j) & 1u) { if (eqpre < need) sel |= 1u << j; ++eqpre; }
        }

        float s8 = 0.f;
#pragma unroll
        for (int i = 0; i < 8; ++i) s8 += __expf(s[i] - m);
        float invd = 1.0f / (s8 + EPSF * zl);

        float o[8];
#pragma unroll
        for (int j = 0; j < 8; ++j)
            o[j] = ((sel >> j) & 1u) ? e[j] * invd : 0.0f;
        float4* dst = (float4*)&out[obase + (size_t)t * NPOOL + (lane << 3)];
        dst[0] = *(float4*)&o[0];
        dst[1] = *(float4*)&o[4];
    }
}

extern "C" void kernel_launch(void* const* d_in, const int* in_sizes, int n_in,
                              void* d_out, int out_size, void* d_ws, size_t ws_size,
                              hipStream_t stream) {
    const float* x   = (const float*)d_in[0];
    const float* W   = (const float*)d_in[1];
    const float* b   = (const float*)d_in[2];
    const float* emb = (const float*)d_in[3];
    float* out  = (float*)d_out;
    float* embT = (float*)d_ws;                       // 64*2048 f32 = 512 KB
    float* proj = embT + 64 * 2048;                   // SK slabs of 8192*384 f32

    size_t base = (size_t)64 * 2048 * 4;
    size_t slab = (size_t)NTOK * PROJN * 4;           // 12.58 MB
    int SK = (ws_size >= base + 4 * slab) ? 4
           : (ws_size >= base + 2 * slab) ? 2 : 1;
    int KS = DMODEL / SK;

    k_norm_emb<<<dim3(512), dim3(256), 0, stream>>>(emb, embT);
    dim3 g2(NTOK / 256, PROJN / 64, SK);
    k_proj<<<g2, dim3(256), 0, stream>>>(x, W, b, proj, KS);
    dim3 g3(NTOK / 32, NHEADS);
    k_router<<<g3, dim3(256), 0, stream>>>(proj, embT, out, SK);
}